// Round 1
// baseline (345.791 us; speedup 1.0000x reference)
//
#include <hip/hip_runtime.h>

// Varlen depthwise conv (Canon layer): out = x + bias + sum_k mask*w[:,k]*x[t+k-2]
// T=65536 tokens, C=768 channels, K=5, NSEQ=16 packed sequences.
// Memory-bound: ~402 MB min traffic -> ~64 us roofline.

#define CC  768          // channels
#define C4V (CC / 4)     // float4 chunks per row = 192 (block size, 3 waves)
#define KK  5            // kernel taps
#define RR  2            // radius
#define TPB 16           // tokens per block (sliding-window reuse)

__global__ __launch_bounds__(C4V) void canon_dwconv_kernel(
    const float4* __restrict__ x4,
    const int*    __restrict__ cu,    // cu_seqlens, nseq+1 entries, cu[nseq]=T
    int nseq,
    const float*  __restrict__ weight, // [C, K] row-major
    const float4* __restrict__ bias4,  // [C/4]
    float4*       __restrict__ out4,
    int T)
{
    const int c4 = threadIdx.x;
    const int t0 = (int)blockIdx.x * TPB;
    const int c  = c4 * 4;

    // Per-thread tap weights for 4 channels (15 KB total table -> L1-resident)
    float w[KK][4];
#pragma unroll
    for (int j = 0; j < 4; ++j)
#pragma unroll
        for (int k = 0; k < KK; ++k)
            w[k][j] = weight[(c + j) * KK + k];

    const float4 b = bias4[c4];

    // Preload sliding window rows t0-2 .. t0+1 (clamped; masks make clamps safe)
    float4 win[KK];
#pragma unroll
    for (int i = 0; i < KK - 1; ++i) {
        int r  = t0 - RR + i;
        int rc = min(max(r, 0), T - 1);
        win[i] = x4[(size_t)rc * C4V + c4];
    }

    // Initial seq_id for t0 (searchsorted-right over cu[1:]): wave-uniform scalar work
    int sid = 0;
    while (sid < nseq && cu[sid + 1] <= t0) ++sid;

#pragma unroll
    for (int tt = 0; tt < TPB; ++tt) {
        const int t = t0 + tt;
        if (t < T) {
            // Load incoming row t+2 into the window slot for this iteration
            {
                int rc = min(t + RR, T - 1);
                win[(tt + KK - 1) % KK] = x4[(size_t)rc * C4V + c4];
            }
            // Advance sequence id (tokens are monotone; cu[nseq]=T bounds the loop)
            while (sid < nseq && cu[sid + 1] <= t) ++sid;
            const int start = cu[sid];
            const int end   = cu[sid + 1];

            // Window rows: r0=t-2, r1=t-1, r2=t, r3=t+1, r4=t+2
            const float4 r0 = win[(tt + 0) % KK];
            const float4 r1 = win[(tt + 1) % KK];
            const float4 r2 = win[(tt + 2) % KK];
            const float4 r3 = win[(tt + 3) % KK];
            const float4 r4 = win[(tt + 4) % KK];

            // Boundary masks (also cover global array edges, since start>=0, end<=T)
            const float m0 = (t - 2 >= start) ? 1.0f : 0.0f;
            const float m1 = (t - 1 >= start) ? 1.0f : 0.0f;
            const float m3 = (t + 1 <  end)  ? 1.0f : 0.0f;
            const float m4 = (t + 2 <  end)  ? 1.0f : 0.0f;

            float4 o;
            o.x = r2.x + b.x + r2.x * w[2][0]
                + r0.x * (w[0][0] * m0) + r1.x * (w[1][0] * m1)
                + r3.x * (w[3][0] * m3) + r4.x * (w[4][0] * m4);
            o.y = r2.y + b.y + r2.y * w[2][1]
                + r0.y * (w[0][1] * m0) + r1.y * (w[1][1] * m1)
                + r3.y * (w[3][1] * m3) + r4.y * (w[4][1] * m4);
            o.z = r2.z + b.z + r2.z * w[2][2]
                + r0.z * (w[0][2] * m0) + r1.z * (w[1][2] * m1)
                + r3.z * (w[3][2] * m3) + r4.z * (w[4][2] * m4);
            o.w = r2.w + b.w + r2.w * w[2][3]
                + r0.w * (w[0][3] * m0) + r1.w * (w[1][3] * m1)
                + r3.w * (w[3][3] * m3) + r4.w * (w[4][3] * m4);

            out4[(size_t)t * C4V + c4] = o;
        }
    }
}

extern "C" void kernel_launch(void* const* d_in, const int* in_sizes, int n_in,
                              void* d_out, int out_size, void* d_ws, size_t ws_size,
                              hipStream_t stream) {
    const float4* x4     = (const float4*)d_in[0];
    const int*    cu     = (const int*)d_in[1];
    const float*  weight = (const float*)d_in[2];
    const float4* bias4  = (const float4*)d_in[3];
    float4*       out4   = (float4*)d_out;

    const int T    = in_sizes[0] / CC;
    const int nseq = in_sizes[1] - 1;

    const int grid = (T + TPB - 1) / TPB;
    canon_dwconv_kernel<<<grid, C4V, 0, stream>>>(x4, cu, nseq, weight, bias4, out4, T);
}